// Round 5
// baseline (3606.342 us; speedup 1.0000x reference)
//
#include <hip/hip_runtime.h>
#include <hip/hip_bf16.h>

#define DM 256
#define NH 8
#define DK 32
#define BSZ 2
#define SEQ 2048
#define ROWS (BSZ*SEQ)   // 4096

// ---------- block reduction helpers (256 threads = 4 waves) ----------
static __device__ __forceinline__ float waveRedSum(float v) {
    #pragma unroll
    for (int off = 32; off > 0; off >>= 1) v += __shfl_down(v, off, 64);
    return v;
}
static __device__ __forceinline__ float waveRedMax(float v) {
    #pragma unroll
    for (int off = 32; off > 0; off >>= 1) v = fmaxf(v, __shfl_down(v, off, 64));
    return v;
}
static __device__ __forceinline__ float blockRedSum(float v, float* red) {
    int lane = threadIdx.x & 63, wid = threadIdx.x >> 6;
    v = waveRedSum(v);
    __syncthreads();
    if (lane == 0) red[wid] = v;
    __syncthreads();
    return red[0] + red[1] + red[2] + red[3];
}
static __device__ __forceinline__ float blockRedMax(float v, float* red) {
    int lane = threadIdx.x & 63, wid = threadIdx.x >> 6;
    v = waveRedMax(v);
    __syncthreads();
    if (lane == 0) red[wid] = v;
    __syncthreads();
    return fmaxf(fmaxf(red[0], red[1]), fmaxf(red[2], red[3]));
}

// ---------- GEMM: Y[4096,256] = X[4096,256] @ W[256,256] + b (all f32) ----
__global__ __launch_bounds__(256) void gemm_kernel(
    const float* __restrict__ X, const float* __restrict__ W,
    const float* __restrict__ bias, float* __restrict__ Y)
{
    __shared__ float xl[32][DM];
    int t = threadIdx.x;
    int r0 = blockIdx.x * 32;
    #pragma unroll 4
    for (int k = 0; k < 32; ++k) xl[k][t] = X[(size_t)(r0 + k) * DM + t];
    __syncthreads();
    float acc[32];
    #pragma unroll
    for (int r = 0; r < 32; ++r) acc[r] = 0.f;
    for (int k = 0; k < DM; k += 4) {
        float w0 = W[(size_t)(k + 0) * DM + t];
        float w1 = W[(size_t)(k + 1) * DM + t];
        float w2 = W[(size_t)(k + 2) * DM + t];
        float w3 = W[(size_t)(k + 3) * DM + t];
        #pragma unroll
        for (int r = 0; r < 32; ++r) {
            float4 xv = *(const float4*)&xl[r][k];
            acc[r] += xv.x * w0 + xv.y * w1 + xv.z * w2 + xv.w * w3;
        }
    }
    float bb = bias[t];
    #pragma unroll 4
    for (int r = 0; r < 32; ++r) Y[(size_t)(r0 + r) * DM + t] = acc[r] + bb;
}

// ---------- residual + layernorm: out = LN(res + y) * g + b ----------
__global__ __launch_bounds__(256) void add_ln_kernel(
    const float* __restrict__ res, int res_bcast,
    const float* __restrict__ y,
    const float* __restrict__ g_, const float* __restrict__ b_,
    float* __restrict__ out)
{
    __shared__ float red[4];
    int row = blockIdx.x, t = threadIdx.x;
    float x = res[res_bcast ? (size_t)t : (size_t)row * DM + t] + y[(size_t)row * DM + t];
    float mean = blockRedSum(x, red) * (1.f / DM);
    float d = x - mean;
    float var = blockRedSum(d * d, red) * (1.f / DM);
    float r = rsqrtf(var + 1e-5f);
    out[(size_t)row * DM + t] = d * r * g_[t] + b_[t];
}

// ---------- attention with distance-decay bias; one row per workgroup ------
// Q/K/V/O layout: [b, s, h*32+d] flat, f32. If qbcast, Q is [h*32+d] (256 floats).
__global__ __launch_bounds__(256) void attn_kernel(
    const float* __restrict__ Q, const float* __restrict__ K, const float* __restrict__ V,
    const float* __restrict__ gam, float* __restrict__ O,
    int peek, int qbcast)
{
    __shared__ float s_row[SEQ];
    __shared__ float qs[DK];
    __shared__ float red[4];
    __shared__ float wtot[4];
    __shared__ float part[4][DK];

    int bh = blockIdx.x;
    int b = bh >> 3, h = bh & 7;
    int i = blockIdx.y;
    int t = threadIdx.x;
    int lane = t & 63, wid = t >> 6;

    size_t base  = ((size_t)b * SEQ) * DM + (size_t)h * DK;      // + j*DM + d
    size_t obase = ((size_t)b * SEQ + i) * DM + (size_t)h * DK;

    int jmax = peek ? i : i - 1;
    if (jmax < 0) {                      // fully masked row -> exact zeros
        if (t < DK) O[obase + t] = 0.f;
        return;
    }
    int nj = jmax + 1;

    if (t < DK) qs[t] = qbcast ? Q[(size_t)h * DK + t] : Q[obase + t];
    __syncthreads();
    float q0[DK];
    #pragma unroll
    for (int c = 0; c < 8; ++c) {
        float4 qv = *(const float4*)&qs[4 * c];
        q0[4*c+0] = qv.x; q0[4*c+1] = qv.y; q0[4*c+2] = qv.z; q0[4*c+3] = qv.w;
    }

    const float scale = 0.17677669529663687f;   // 1/sqrt(32)
    // Phase 1: scores
    for (int j = t; j < nj; j += 256) {
        const float4* kp = (const float4*)(K + base + (size_t)j * DM);
        float acc = 0.f;
        #pragma unroll
        for (int c = 0; c < 8; ++c) {
            float4 kv = kp[c];
            acc += q0[4*c+0]*kv.x + q0[4*c+1]*kv.y + q0[4*c+2]*kv.z + q0[4*c+3]*kv.w;
        }
        s_row[j] = acc * scale;
    }
    __syncthreads();

    // Phase 2: first softmax stats
    float m = -1e30f;
    for (int j = t; j < nj; j += 256) m = fmaxf(m, s_row[j]);
    m = blockRedMax(m, red);
    float l = 0.f;
    for (int j = t; j < nj; j += 256) l += __expf(s_row[j] - m);
    l = blockRedSum(l, red);
    float linv = 1.f / l;

    // Phase 3: cumsum of sm (block scan over contiguous 8-chunks) -> dist -> eff
    float g = gam[h];
    float gamma = -log1pf(__expf(g));            // -softplus(gam)
    int j0 = t * 8;
    float sm[8];
    float lsum = 0.f;
    #pragma unroll
    for (int c = 0; c < 8; ++c) {
        int j = j0 + c;
        float v = (j < nj) ? __expf(s_row[j] - m) * linv : 0.f;
        sm[c] = v; lsum += v;
    }
    float x = lsum;
    #pragma unroll
    for (int off = 1; off < 64; off <<= 1) {
        float yv = __shfl_up(x, off, 64);
        if (lane >= off) x += yv;
    }
    if (lane == 63) wtot[wid] = x;
    __syncthreads();
    float woff = 0.f;
    for (int w = 0; w < wid; ++w) woff += wtot[w];
    float cum = woff + x - lsum;                 // exclusive prefix
    #pragma unroll
    for (int c = 0; c < 8; ++c) {
        int j = j0 + c;
        if (j < nj) {
            cum += sm[c];
            float pos = (float)(i - j);
            float dist = sqrtf(fmaxf((1.f - cum) * pos, 0.f));
            float eff = __expf(dist * gamma);
            eff = fminf(fmaxf(eff, 1e-5f), 1e5f);
            s_row[j] = s_row[j] * eff;
        }
    }
    __syncthreads();

    // Phase 4: second softmax stats
    float m2 = -1e30f;
    for (int j = t; j < nj; j += 256) m2 = fmaxf(m2, s_row[j]);
    m2 = blockRedMax(m2, red);
    float l2 = 0.f;
    for (int j = t; j < nj; j += 256) l2 += __expf(s_row[j] - m2);
    l2 = blockRedSum(l2, red);
    float l2inv = 1.f / l2;

    // Phase 5: O = P @ V
    float acc[DK];
    #pragma unroll
    for (int d = 0; d < DK; ++d) acc[d] = 0.f;
    for (int j = t; j < nj; j += 256) {
        float p = __expf(s_row[j] - m2) * l2inv;
        const float4* vp = (const float4*)(V + base + (size_t)j * DM);
        #pragma unroll
        for (int c = 0; c < 8; ++c) {
            float4 vv = vp[c];
            acc[4*c+0] += p * vv.x; acc[4*c+1] += p * vv.y;
            acc[4*c+2] += p * vv.z; acc[4*c+3] += p * vv.w;
        }
    }
    #pragma unroll
    for (int d = 0; d < DK; ++d) {
        #pragma unroll
        for (int off = 32; off > 0; off >>= 1) acc[d] += __shfl_down(acc[d], off, 64);
    }
    __syncthreads();
    if (lane == 0) {
        #pragma unroll
        for (int d = 0; d < DK; ++d) part[wid][d] = acc[d];
    }
    __syncthreads();
    if (t < DK) O[obase + t] = part[0][t] + part[1][t] + part[2][t] + part[3][t];
}

// ---------- small precompute: q3row = know@W3q+b3q; key8 = sigmoid heads ---
__global__ __launch_bounds__(256) void precompute_kernel(
    const float* __restrict__ know,
    const float* __restrict__ W3q, const float* __restrict__ b3q,
    const float* __restrict__ lkW, const float* __restrict__ lkb,
    float* __restrict__ q3row, float* __restrict__ key8)
{
    __shared__ float kn[DM];
    int t = threadIdx.x;
    kn[t] = know[t];
    __syncthreads();
    float acc = b3q[t];
    for (int c = 0; c < DM; ++c) acc += kn[c] * W3q[(size_t)c * DM + t];
    q3row[t] = acc;
    float bk = lkb[t];
    for (int h = 0; h < NH; ++h) {
        float a = bk;
        #pragma unroll
        for (int c = 0; c < DK; ++c) a += kn[h * DK + c] * lkW[(size_t)c * DM + t];
        key8[(size_t)h * DM + t] = 1.f / (1.f + __expf(-a));
    }
}

// ---------- final readout (f32 output!) ----------
__global__ __launch_bounds__(256) void readout_kernel(
    const float* __restrict__ h3, const float* __restrict__ qe,
    const float* __restrict__ key8,
    const float* __restrict__ lvW, const float* __restrict__ lvb,
    float* __restrict__ out)
{
    __shared__ float hrow[DM], qrow[DM];
    __shared__ float red[4];
    int n = blockIdx.x, t = threadIdx.x;
    hrow[t] = h3[(size_t)n * DM + t];
    qrow[t] = qe[(size_t)n * DM + t];
    __syncthreads();
    float beta[NH];
    for (int h = 0; h < NH; ++h)
        beta[h] = blockRedSum(key8[(size_t)h * DM + t] * qrow[t], red);
    float bv = lvb[t];
    float vh[NH];
    for (int h = 0; h < NH; ++h) {
        float a = bv;
        #pragma unroll
        for (int c = 0; c < DK; ++c) a += hrow[h * DK + c] * lvW[(size_t)c * DM + t];
        vh[h] = 1.f / (1.f + __expf(-a));
    }
    float mb = beta[0];
    #pragma unroll
    for (int h = 1; h < NH; ++h) mb = fmaxf(mb, beta[h]);
    float se = 0.f, eh[NH];
    #pragma unroll
    for (int h = 0; h < NH; ++h) { eh[h] = __expf(beta[h] - mb); se += eh[h]; }
    float sinv = 1.f / se;
    float o = 0.f;
    #pragma unroll
    for (int h = 0; h < NH; ++h) o += eh[h] * sinv * vh[h];
    out[(size_t)n * DM + t] = o;
}

extern "C" void kernel_launch(void* const* d_in, const int* in_sizes, int n_in,
                              void* d_out, int out_size, void* d_ws, size_t ws_size,
                              hipStream_t stream) {
    (void)in_sizes; (void)n_in; (void)out_size; (void)ws_size;
    const float* q_emb  = (const float*)d_in[0];
    const float* qa_emb = (const float*)d_in[1];
    const float* b1_Wq = (const float*)d_in[2];
    const float* b1_bq = (const float*)d_in[3];
    const float* b1_Wv = (const float*)d_in[4];
    const float* b1_bv = (const float*)d_in[5];
    const float* b1_Wo = (const float*)d_in[6];
    const float* b1_bo = (const float*)d_in[7];
    const float* b1_gam = (const float*)d_in[8];
    const float* b1_lng = (const float*)d_in[9];
    const float* b1_lnb = (const float*)d_in[10];
    const float* b2_Wq = (const float*)d_in[11];
    const float* b2_bq = (const float*)d_in[12];
    const float* b2_Wv = (const float*)d_in[13];
    const float* b2_bv = (const float*)d_in[14];
    const float* b2_Wo = (const float*)d_in[15];
    const float* b2_bo = (const float*)d_in[16];
    const float* b2_gam = (const float*)d_in[17];
    const float* b2_lng = (const float*)d_in[18];
    const float* b2_lnb = (const float*)d_in[19];
    const float* b3_Wq = (const float*)d_in[20];
    const float* b3_bq = (const float*)d_in[21];
    const float* b3_Wk = (const float*)d_in[22];
    const float* b3_bk = (const float*)d_in[23];
    const float* b3_Wv = (const float*)d_in[24];
    const float* b3_bv = (const float*)d_in[25];
    const float* b3_Wo = (const float*)d_in[26];
    const float* b3_bo = (const float*)d_in[27];
    const float* b3_gam = (const float*)d_in[28];
    const float* b3_lng = (const float*)d_in[29];
    const float* b3_lnb = (const float*)d_in[30];
    const float* know  = (const float*)d_in[31];
    const float* lk_W  = (const float*)d_in[32];
    const float* lk_b  = (const float*)d_in[33];
    const float* lv_W  = (const float*)d_in[34];
    const float* lv_b  = (const float*)d_in[35];

    const size_t SLAB = (size_t)ROWS * DM;  // 1,048,576 floats = 4 MB
    float* A = (float*)d_ws;
    float* B = A + SLAB;
    float* C = B + SLAB;
    float* D = C + SLAB;
    float* E = D + SLAB;
    float* F = E + SLAB;
    float* q3row = F + SLAB;          // 256
    float* key8  = q3row + DM;        // 8*256

    dim3 blk(256);
    dim3 ggrid(ROWS / 32);
    dim3 agrid(BSZ * NH, SEQ);
    dim3 rgrid(ROWS);

    // ---- block 1 (self-attn on q_emb, k shares q weights) ----
    gemm_kernel<<<ggrid, blk, 0, stream>>>(q_emb, b1_Wq, b1_bq, A);      // q1 (=k1)
    gemm_kernel<<<ggrid, blk, 0, stream>>>(q_emb, b1_Wv, b1_bv, B);      // v1
    attn_kernel<<<agrid, blk, 0, stream>>>(A, A, B, b1_gam, C, 1, 0);    // att1
    gemm_kernel<<<ggrid, blk, 0, stream>>>(C, b1_Wo, b1_bo, D);          // y1
    add_ln_kernel<<<rgrid, blk, 0, stream>>>(q_emb, 0, D, b1_lng, b1_lnb, E);  // hq

    // ---- block 2 (self-attn on qa_emb) ----
    gemm_kernel<<<ggrid, blk, 0, stream>>>(qa_emb, b2_Wq, b2_bq, A);
    gemm_kernel<<<ggrid, blk, 0, stream>>>(qa_emb, b2_Wv, b2_bv, B);
    attn_kernel<<<agrid, blk, 0, stream>>>(A, A, B, b2_gam, C, 1, 0);
    gemm_kernel<<<ggrid, blk, 0, stream>>>(C, b2_Wo, b2_bo, D);
    add_ln_kernel<<<rgrid, blk, 0, stream>>>(qa_emb, 0, D, b2_lng, b2_lnb, F); // ha

    // ---- block 3 (query = broadcast know; k from hq, v from ha; strict mask) ----
    precompute_kernel<<<dim3(1), blk, 0, stream>>>(know, b3_Wq, b3_bq, lk_W, lk_b, q3row, key8);
    gemm_kernel<<<ggrid, blk, 0, stream>>>(E, b3_Wk, b3_bk, A);          // k3
    gemm_kernel<<<ggrid, blk, 0, stream>>>(F, b3_Wv, b3_bv, B);          // v3
    attn_kernel<<<agrid, blk, 0, stream>>>(q3row, A, B, b3_gam, C, 0, 1);
    gemm_kernel<<<ggrid, blk, 0, stream>>>(C, b3_Wo, b3_bo, D);          // y3
    add_ln_kernel<<<rgrid, blk, 0, stream>>>(know, 1, D, b3_lng, b3_lnb, E);   // h3

    // ---- readout ----
    readout_kernel<<<rgrid, blk, 0, stream>>>(E, q_emb, key8, lv_W, lv_b,
                                              (float*)d_out);
}

// Round 6
// 3407.757 us; speedup vs baseline: 1.0583x; 1.0583x over previous
//
#include <hip/hip_runtime.h>
#include <hip/hip_bf16.h>

#define DM 256
#define NH 8
#define DK 32
#define BSZ 2
#define SEQ 2048
#define ROWS (BSZ*SEQ)   // 4096
#define RT 8             // query rows per attention tile
#define SROW 2112        // 2048 + 64 swizzle pad (phys = j + (j>>5))

// ---------- block reduction helpers (256 threads = 4 waves) ----------
static __device__ __forceinline__ float waveRedSum(float v) {
    #pragma unroll
    for (int off = 32; off > 0; off >>= 1) v += __shfl_down(v, off, 64);
    return v;
}
static __device__ __forceinline__ float blockRedSum(float v, float* red) {
    int lane = threadIdx.x & 63, wid = threadIdx.x >> 6;
    v = waveRedSum(v);
    __syncthreads();
    if (lane == 0) red[wid] = v;
    __syncthreads();
    return red[0] + red[1] + red[2] + red[3];
}

// ---------- GEMM: Y[4096,256] = X[4096,256] @ W[256,256] + b (all f32) ----
__global__ __launch_bounds__(256) void gemm_kernel(
    const float* __restrict__ X, const float* __restrict__ W,
    const float* __restrict__ bias, float* __restrict__ Y)
{
    __shared__ float xl[32][DM];
    int t = threadIdx.x;
    int r0 = blockIdx.x * 32;
    #pragma unroll 4
    for (int k = 0; k < 32; ++k) xl[k][t] = X[(size_t)(r0 + k) * DM + t];
    __syncthreads();
    float acc[32];
    #pragma unroll
    for (int r = 0; r < 32; ++r) acc[r] = 0.f;
    for (int k = 0; k < DM; k += 4) {
        float w0 = W[(size_t)(k + 0) * DM + t];
        float w1 = W[(size_t)(k + 1) * DM + t];
        float w2 = W[(size_t)(k + 2) * DM + t];
        float w3 = W[(size_t)(k + 3) * DM + t];
        #pragma unroll
        for (int r = 0; r < 32; ++r) {
            float4 xv = *(const float4*)&xl[r][k];
            acc[r] += xv.x * w0 + xv.y * w1 + xv.z * w2 + xv.w * w3;
        }
    }
    float bb = bias[t];
    #pragma unroll 4
    for (int r = 0; r < 32; ++r) Y[(size_t)(r0 + r) * DM + t] = acc[r] + bb;
}

// ---------- residual + layernorm ----------
__global__ __launch_bounds__(256) void add_ln_kernel(
    const float* __restrict__ res, int res_bcast,
    const float* __restrict__ y,
    const float* __restrict__ g_, const float* __restrict__ b_,
    float* __restrict__ out)
{
    __shared__ float red[4];
    int row = blockIdx.x, t = threadIdx.x;
    float x = res[res_bcast ? (size_t)t : (size_t)row * DM + t] + y[(size_t)row * DM + t];
    float mean = blockRedSum(x, red) * (1.f / DM);
    float d = x - mean;
    float var = blockRedSum(d * d, red) * (1.f / DM);
    float r = rsqrtf(var + 1e-5f);
    out[(size_t)row * DM + t] = d * r * g_[t] + b_[t];
}

// ---------- tiled attention with distance-decay bias ----------
// 8 query rows per workgroup. Score tile in LDS with +1-per-32 swizzle.
// Grid: (SEQ/RT, BSZ*NH). Q/K/V/O layout [b,s,h*32+d]; qbcast: Q is [h*32+d].
__global__ __launch_bounds__(256) void attn_tile_kernel(
    const float* __restrict__ Q, const float* __restrict__ K, const float* __restrict__ V,
    const float* __restrict__ gam, float* __restrict__ O,
    int peek, int qbcast)
{
    __shared__ float S[RT * SROW];
    __shared__ float qs[RT][DK];
    __shared__ float l2inv_s[RT];

    int bh = blockIdx.y;
    int b = bh >> 3, h = bh & 7;
    int i0 = blockIdx.x * RT;
    int t = threadIdx.x;

    size_t base = ((size_t)b * SEQ) * DM + (size_t)h * DK;

    {   // load Q tile
        int r = t >> 5, d = t & 31;
        qs[r][d] = qbcast ? Q[(size_t)h * DK + d]
                          : Q[base + (size_t)(i0 + r) * DM + d];
    }
    __syncthreads();

    int jmaxAll = peek ? (i0 + RT - 1) : (i0 + RT - 2);
    int njAll = jmaxAll + 1;                  // >= 7 always
    const float scale = 0.17677669529663687f; // 1/sqrt(32)

    // Phase 1: S[r][j] = (Q[r] . K[j]) * scale  — K row loaded once, 8x reuse
    for (int j = t; j < njAll; j += 256) {
        const float4* kp = (const float4*)(K + base + (size_t)j * DM);
        float4 kv[8];
        #pragma unroll
        for (int q = 0; q < 8; ++q) kv[q] = kp[q];
        int sj = j + (j >> 5);
        #pragma unroll
        for (int r = 0; r < RT; ++r) {
            float s = 0.f;
            #pragma unroll
            for (int q = 0; q < 8; ++q) {
                float4 qv = *(const float4*)&qs[r][4 * q];
                s += qv.x * kv[q].x + qv.y * kv[q].y + qv.z * kv[q].z + qv.w * kv[q].w;
            }
            S[r * SROW + sj] = s * scale;
        }
    }
    __syncthreads();

    // Phases 2-4: 32 threads per row, contiguous 64-col chunks (swizzled banks)
    int r = t >> 5, c = t & 31;
    int i = i0 + r;
    int nj = peek ? (i + 1) : i;              // may be 0 (attn3, i==0)
    int jlo = c * 64;
    int jhiA = nj < jlo + 64 ? nj : jlo + 64;
    float* Sr = S + r * SROW;

    float m = -1e30f;
    for (int j = jlo; j < jhiA; ++j) m = fmaxf(m, Sr[j + (j >> 5)]);
    #pragma unroll
    for (int off = 16; off; off >>= 1) m = fmaxf(m, __shfl_xor(m, off, 64));

    float lsum = 0.f;
    for (int j = jlo; j < jhiA; ++j) lsum += __expf(Sr[j + (j >> 5)] - m);
    float l = lsum;
    #pragma unroll
    for (int off = 16; off; off >>= 1) l += __shfl_xor(l, off, 64);
    float linv = 1.f / l;

    // exclusive scan of per-lane sums (width-32 segments)
    float x = lsum;
    #pragma unroll
    for (int off = 1; off < 32; off <<= 1) {
        float y = __shfl_up(x, off, 32);
        if (c >= off) x += y;
    }
    float cum = (x - lsum) * linv;

    float gamma = -log1pf(__expf(gam[h]));    // -softplus
    float m2 = -1e30f;
    for (int j = jlo; j < jhiA; ++j) {
        float s = Sr[j + (j >> 5)];
        cum += __expf(s - m) * linv;
        float pos = (float)(i - j);
        float dist = sqrtf(fmaxf((1.f - cum) * pos, 0.f));
        float eff = __expf(dist * gamma);
        eff = fminf(fmaxf(eff, 1e-5f), 1e5f);
        float s2 = s * eff;
        Sr[j + (j >> 5)] = s2;
        m2 = fmaxf(m2, s2);
    }
    #pragma unroll
    for (int off = 16; off; off >>= 1) m2 = fmaxf(m2, __shfl_xor(m2, off, 64));

    // pass d: store unnormalized p = exp(s2-m2); zero-fill up to njAll
    float l2 = 0.f;
    int jhiB = njAll < jlo + 64 ? njAll : jlo + 64;
    for (int j = jlo; j < jhiB; ++j) {
        float e = 0.f;
        if (j < nj) { e = __expf(Sr[j + (j >> 5)] - m2); l2 += e; }
        Sr[j + (j >> 5)] = e;
    }
    #pragma unroll
    for (int off = 16; off; off >>= 1) l2 += __shfl_xor(l2, off, 64);
    if (c == 0) l2inv_s[r] = (nj > 0) ? (1.f / l2) : 0.f;
    __syncthreads();

    // Phase 5 PV: lane = (jg, quad); 8 lanes cover one coalesced 128B V row
    int jg = t >> 3, q = t & 7;
    float acc[RT][4];
    #pragma unroll
    for (int rr = 0; rr < RT; ++rr) { acc[rr][0]=0.f; acc[rr][1]=0.f; acc[rr][2]=0.f; acc[rr][3]=0.f; }
    for (int j = jg; j < njAll; j += 32) {
        float4 v = *(const float4*)(V + base + (size_t)j * DM + 4 * q);
        int sj = j + (j >> 5);
        #pragma unroll
        for (int rr = 0; rr < RT; ++rr) {
            float p = S[rr * SROW + sj];
            acc[rr][0] += p * v.x; acc[rr][1] += p * v.y;
            acc[rr][2] += p * v.z; acc[rr][3] += p * v.w;
        }
    }
    __syncthreads();          // everyone done reading S -> reuse as scratch
    #pragma unroll
    for (int rr = 0; rr < RT; ++rr) {
        #pragma unroll
        for (int xx = 0; xx < 4; ++xx)
            S[t * 33 + rr * 4 + xx] = acc[rr][xx];   // stride 33: conflict-free
    }
    __syncthreads();
    {
        int r2 = t >> 5, d = t & 31, q2 = d >> 2, x2 = d & 3;
        float sum = 0.f;
        #pragma unroll 8
        for (int jg2 = 0; jg2 < 32; ++jg2)
            sum += S[(jg2 * 8 + q2) * 33 + r2 * 4 + x2];
        int ii = i0 + r2;
        int njr = peek ? (ii + 1) : ii;
        O[base + (size_t)ii * DM + d] = (njr > 0) ? sum * l2inv_s[r2] : 0.f;
    }
}

// ---------- small precompute: q3row = know@W3q+b3q; key8 = sigmoid heads ---
__global__ __launch_bounds__(256) void precompute_kernel(
    const float* __restrict__ know,
    const float* __restrict__ W3q, const float* __restrict__ b3q,
    const float* __restrict__ lkW, const float* __restrict__ lkb,
    float* __restrict__ q3row, float* __restrict__ key8)
{
    __shared__ float kn[DM];
    int t = threadIdx.x;
    kn[t] = know[t];
    __syncthreads();
    float acc = b3q[t];
    for (int c = 0; c < DM; ++c) acc += kn[c] * W3q[(size_t)c * DM + t];
    q3row[t] = acc;
    float bk = lkb[t];
    for (int h = 0; h < NH; ++h) {
        float a = bk;
        #pragma unroll
        for (int c = 0; c < DK; ++c) a += kn[h * DK + c] * lkW[(size_t)c * DM + t];
        key8[(size_t)h * DM + t] = 1.f / (1.f + __expf(-a));
    }
}

// ---------- final readout (f32 output) ----------
__global__ __launch_bounds__(256) void readout_kernel(
    const float* __restrict__ h3, const float* __restrict__ qe,
    const float* __restrict__ key8,
    const float* __restrict__ lvW, const float* __restrict__ lvb,
    float* __restrict__ out)
{
    __shared__ float hrow[DM], qrow[DM];
    __shared__ float red[4];
    int n = blockIdx.x, t = threadIdx.x;
    hrow[t] = h3[(size_t)n * DM + t];
    qrow[t] = qe[(size_t)n * DM + t];
    __syncthreads();
    float beta[NH];
    for (int h = 0; h < NH; ++h)
        beta[h] = blockRedSum(key8[(size_t)h * DM + t] * qrow[t], red);
    float bv = lvb[t];
    float vh[NH];
    for (int h = 0; h < NH; ++h) {
        float a = bv;
        #pragma unroll
        for (int c = 0; c < DK; ++c) a += hrow[h * DK + c] * lvW[(size_t)c * DM + t];
        vh[h] = 1.f / (1.f + __expf(-a));
    }
    float mb = beta[0];
    #pragma unroll
    for (int h = 1; h < NH; ++h) mb = fmaxf(mb, beta[h]);
    float se = 0.f, eh[NH];
    #pragma unroll
    for (int h = 0; h < NH; ++h) { eh[h] = __expf(beta[h] - mb); se += eh[h]; }
    float sinv = 1.f / se;
    float o = 0.f;
    #pragma unroll
    for (int h = 0; h < NH; ++h) o += eh[h] * sinv * vh[h];
    out[(size_t)n * DM + t] = o;
}

extern "C" void kernel_launch(void* const* d_in, const int* in_sizes, int n_in,
                              void* d_out, int out_size, void* d_ws, size_t ws_size,
                              hipStream_t stream) {
    (void)in_sizes; (void)n_in; (void)out_size; (void)ws_size;
    const float* q_emb  = (const float*)d_in[0];
    const float* qa_emb = (const float*)d_in[1];
    const float* b1_Wq = (const float*)d_in[2];
    const float* b1_bq = (const float*)d_in[3];
    const float* b1_Wv = (const float*)d_in[4];
    const float* b1_bv = (const float*)d_in[5];
    const float* b1_Wo = (const float*)d_in[6];
    const float* b1_bo = (const float*)d_in[7];
    const float* b1_gam = (const float*)d_in[8];
    const float* b1_lng = (const float*)d_in[9];
    const float* b1_lnb = (const float*)d_in[10];
    const float* b2_Wq = (const float*)d_in[11];
    const float* b2_bq = (const float*)d_in[12];
    const float* b2_Wv = (const float*)d_in[13];
    const float* b2_bv = (const float*)d_in[14];
    const float* b2_Wo = (const float*)d_in[15];
    const float* b2_bo = (const float*)d_in[16];
    const float* b2_gam = (const float*)d_in[17];
    const float* b2_lng = (const float*)d_in[18];
    const float* b2_lnb = (const float*)d_in[19];
    const float* b3_Wq = (const float*)d_in[20];
    const float* b3_bq = (const float*)d_in[21];
    const float* b3_Wk = (const float*)d_in[22];
    const float* b3_bk = (const float*)d_in[23];
    const float* b3_Wv = (const float*)d_in[24];
    const float* b3_bv = (const float*)d_in[25];
    const float* b3_Wo = (const float*)d_in[26];
    const float* b3_bo = (const float*)d_in[27];
    const float* b3_gam = (const float*)d_in[28];
    const float* b3_lng = (const float*)d_in[29];
    const float* b3_lnb = (const float*)d_in[30];
    const float* know  = (const float*)d_in[31];
    const float* lk_W  = (const float*)d_in[32];
    const float* lk_b  = (const float*)d_in[33];
    const float* lv_W  = (const float*)d_in[34];
    const float* lv_b  = (const float*)d_in[35];

    const size_t SLAB = (size_t)ROWS * DM;  // 1,048,576 floats = 4 MB
    float* A = (float*)d_ws;
    float* B = A + SLAB;
    float* C = B + SLAB;
    float* D = C + SLAB;
    float* E = D + SLAB;
    float* F = E + SLAB;
    float* q3row = F + SLAB;          // 256
    float* key8  = q3row + DM;        // 8*256

    dim3 blk(256);
    dim3 ggrid(ROWS / 32);
    dim3 agrid(SEQ / RT, BSZ * NH);
    dim3 rgrid(ROWS);

    // ---- block 1 (self-attn on q_emb, k shares q weights) ----
    gemm_kernel<<<ggrid, blk, 0, stream>>>(q_emb, b1_Wq, b1_bq, A);      // q1 (=k1)
    gemm_kernel<<<ggrid, blk, 0, stream>>>(q_emb, b1_Wv, b1_bv, B);      // v1
    attn_tile_kernel<<<agrid, blk, 0, stream>>>(A, A, B, b1_gam, C, 1, 0);
    gemm_kernel<<<ggrid, blk, 0, stream>>>(C, b1_Wo, b1_bo, D);          // y1
    add_ln_kernel<<<rgrid, blk, 0, stream>>>(q_emb, 0, D, b1_lng, b1_lnb, E);  // hq

    // ---- block 2 (self-attn on qa_emb) ----
    gemm_kernel<<<ggrid, blk, 0, stream>>>(qa_emb, b2_Wq, b2_bq, A);
    gemm_kernel<<<ggrid, blk, 0, stream>>>(qa_emb, b2_Wv, b2_bv, B);
    attn_tile_kernel<<<agrid, blk, 0, stream>>>(A, A, B, b2_gam, C, 1, 0);
    gemm_kernel<<<ggrid, blk, 0, stream>>>(C, b2_Wo, b2_bo, D);
    add_ln_kernel<<<rgrid, blk, 0, stream>>>(qa_emb, 0, D, b2_lng, b2_lnb, F); // ha

    // ---- block 3 (query = broadcast know; k from hq, v from ha; strict mask) ----
    precompute_kernel<<<dim3(1), blk, 0, stream>>>(know, b3_Wq, b3_bq, lk_W, lk_b, q3row, key8);
    gemm_kernel<<<ggrid, blk, 0, stream>>>(E, b3_Wk, b3_bk, A);          // k3
    gemm_kernel<<<ggrid, blk, 0, stream>>>(F, b3_Wv, b3_bv, B);          // v3
    attn_tile_kernel<<<agrid, blk, 0, stream>>>(q3row, A, B, b3_gam, C, 0, 1);
    gemm_kernel<<<ggrid, blk, 0, stream>>>(C, b3_Wo, b3_bo, D);          // y3
    add_ln_kernel<<<rgrid, blk, 0, stream>>>(know, 1, D, b3_lng, b3_lnb, E);   // h3

    // ---- readout ----
    readout_kernel<<<rgrid, blk, 0, stream>>>(E, q_emb, key8, lv_W, lv_b,
                                              (float*)d_out);
}